// Round 1
// baseline (657.173 us; speedup 1.0000x reference)
//
#include <hip/hip_runtime.h>
#include <hip/hip_bf16.h>

// Problem constants: B=2, L=256, D=512, H=8, dk=64
#define L_SEQ 256
#define D_MODEL 512
#define N_HEADS 8
#define DK 64
#define N_BATCH 2
#define BH (N_BATCH * N_HEADS)   // 16

// ---------------------------------------------------------------------------
// Generic NT GEMM: out[r,c] = sum_e X[r,e] * W[c,e] + bias[c]
// rows = cols = K = 512 fixed. 32x32 output tile per 256-thread block.
// split_heads==1: write out[(b*8+h)*L*DK + l*DK + d] with r=b*L+l, c=h*DK+d
// split_heads==0: write out[r*512 + c]
// ---------------------------------------------------------------------------
__global__ __launch_bounds__(256) void gemm_nt(
    const float* __restrict__ X, const float* __restrict__ W,
    const float* __restrict__ bias, float* __restrict__ out, int split_heads)
{
    __shared__ float Xs[32][33];
    __shared__ float Ws[32][33];

    const int tid  = threadIdx.x;
    const int row0 = blockIdx.x * 32;
    const int col0 = blockIdx.y * 32;
    const int tx = tid & 31;   // output col within tile
    const int ty = tid >> 5;   // 0..7, output rows ty, ty+8, ty+16, ty+24

    float acc0 = 0.f, acc1 = 0.f, acc2 = 0.f, acc3 = 0.f;

    const int lr = tid >> 3;        // 0..31
    const int lc = (tid & 7) << 2;  // 0,4,...,28

    for (int k0 = 0; k0 < 512; k0 += 32) {
        float4 xv = *(const float4*)&X[(size_t)(row0 + lr) * 512 + k0 + lc];
        float4 wv = *(const float4*)&W[(size_t)(col0 + lr) * 512 + k0 + lc];
        Xs[lr][lc + 0] = xv.x; Xs[lr][lc + 1] = xv.y;
        Xs[lr][lc + 2] = xv.z; Xs[lr][lc + 3] = xv.w;
        Ws[lr][lc + 0] = wv.x; Ws[lr][lc + 1] = wv.y;
        Ws[lr][lc + 2] = wv.z; Ws[lr][lc + 3] = wv.w;
        __syncthreads();
#pragma unroll
        for (int kk = 0; kk < 32; ++kk) {
            float w = Ws[tx][kk];
            acc0 += Xs[ty][kk] * w;
            acc1 += Xs[ty + 8][kk] * w;
            acc2 += Xs[ty + 16][kk] * w;
            acc3 += Xs[ty + 24][kk] * w;
        }
        __syncthreads();
    }

    const int c = col0 + tx;
    const float bv = bias[c];
    float accs[4] = {acc0, acc1, acc2, acc3};
#pragma unroll
    for (int r = 0; r < 4; ++r) {
        const int row = row0 + ty + r * 8;
        const float val = accs[r] + bv;
        if (split_heads) {
            const int b = row >> 8, l = row & 255;
            const int h = c >> 6,  d = c & 63;
            out[(size_t)((b * N_HEADS + h) * L_SEQ + l) * DK + d] = val;
        } else {
            out[(size_t)row * 512 + c] = val;
        }
    }
}

// ---------------------------------------------------------------------------
// Fused attention with relative-position bias.
// One block (256 threads) per (bh, i). Streams rel_q[bh,i] and rel_v[bh,i]
// (64 KB each) exactly once with coalesced float4 loads.
// ---------------------------------------------------------------------------
__global__ __launch_bounds__(256) void attn_rel(
    const float* __restrict__ q, const float* __restrict__ k,
    const float* __restrict__ v, const int* __restrict__ mask,
    const float* __restrict__ relq, const float* __restrict__ relv,
    float* __restrict__ ctx)
{
    const int bh = blockIdx.x >> 8;    // 0..15
    const int i  = blockIdx.x & 255;
    const int b  = bh >> 3;
    const int h  = bh & 7;

    const int t    = threadIdx.x;
    const int lane = t & 63;
    const int wave = t >> 6;

    __shared__ float q_s[64];
    __shared__ float sc[256];
    __shared__ float red[8];
    __shared__ float ctxp[4][64];

    const float scale = 0.125f;  // 1/sqrt(64)

    if (t < 64) q_s[t] = q[(size_t)(bh * L_SEQ + i) * DK + t];
    __syncthreads();

    const int jgrp = t >> 4;          // 0..15  (which j within a pass)
    const int d0   = (t & 15) << 2;   // 0,4,...,60

    const float q0 = q_s[d0], q1 = q_s[d0 + 1], q2 = q_s[d0 + 2], q3 = q_s[d0 + 3];

    const float* relq_row = relq + ((size_t)bh * L_SEQ + i) * L_SEQ * DK;
    const float* k_bh = k + (size_t)bh * L_SEQ * DK;
    const int* mask_row = mask + (size_t)(b * L_SEQ + i) * L_SEQ;

    // ---- scores: s_j = sum_d q_d * (scale*k_jd + relq_jd) ----
#pragma unroll 4
    for (int p = 0; p < 16; ++p) {
        const int j = p * 16 + jgrp;
        float4 rq = *(const float4*)&relq_row[(size_t)j * DK + d0];
        float4 kk = *(const float4*)&k_bh[(size_t)j * DK + d0];
        float s = q0 * fmaf(scale, kk.x, rq.x)
                + q1 * fmaf(scale, kk.y, rq.y)
                + q2 * fmaf(scale, kk.z, rq.z)
                + q3 * fmaf(scale, kk.w, rq.w);
        s += __shfl_xor(s, 1);
        s += __shfl_xor(s, 2);
        s += __shfl_xor(s, 4);
        s += __shfl_xor(s, 8);
        if ((t & 15) == 0) {
            const int m = mask_row[j];
            sc[j] = (m == 0) ? -1e9f : s;
        }
    }
    __syncthreads();

    // ---- softmax over 256 scores ----
    const float s_own = sc[t];
    float mval = s_own;
#pragma unroll
    for (int o = 32; o >= 1; o >>= 1) mval = fmaxf(mval, __shfl_xor(mval, o));
    if (lane == 0) red[wave] = mval;
    __syncthreads();
    mval = fmaxf(fmaxf(red[0], red[1]), fmaxf(red[2], red[3]));

    const float e = __expf(s_own - mval);
    float ssum = e;
#pragma unroll
    for (int o = 32; o >= 1; o >>= 1) ssum += __shfl_xor(ssum, o);
    if (lane == 0) red[4 + wave] = ssum;
    __syncthreads();
    ssum = red[4] + red[5] + red[6] + red[7];

    sc[t] = e / ssum;   // p_j
    __syncthreads();

    // ---- ctx_d = sum_j p_j * (v_jd + relv_jd) ----
    const float* relv_row = relv + ((size_t)bh * L_SEQ + i) * L_SEQ * DK;
    const float* v_bh = v + (size_t)bh * L_SEQ * DK;

    float a0 = 0.f, a1 = 0.f, a2 = 0.f, a3 = 0.f;
#pragma unroll 4
    for (int p = 0; p < 16; ++p) {
        const int j = p * 16 + jgrp;
        float4 rv = *(const float4*)&relv_row[(size_t)j * DK + d0];
        float4 vv = *(const float4*)&v_bh[(size_t)j * DK + d0];
        const float pw = sc[j];
        a0 = fmaf(pw, vv.x + rv.x, a0);
        a1 = fmaf(pw, vv.y + rv.y, a1);
        a2 = fmaf(pw, vv.z + rv.z, a2);
        a3 = fmaf(pw, vv.w + rv.w, a3);
    }
    // reduce the 4 lane-groups (lane, lane^16, lane^32, lane^48) in each wave
    a0 += __shfl_xor(a0, 16); a0 += __shfl_xor(a0, 32);
    a1 += __shfl_xor(a1, 16); a1 += __shfl_xor(a1, 32);
    a2 += __shfl_xor(a2, 16); a2 += __shfl_xor(a2, 32);
    a3 += __shfl_xor(a3, 16); a3 += __shfl_xor(a3, 32);
    if (lane < 16) {
        ctxp[wave][lane * 4 + 0] = a0;
        ctxp[wave][lane * 4 + 1] = a1;
        ctxp[wave][lane * 4 + 2] = a2;
        ctxp[wave][lane * 4 + 3] = a3;
    }
    __syncthreads();

    if (t < 64) {
        const float r = ctxp[0][t] + ctxp[1][t] + ctxp[2][t] + ctxp[3][t];
        // ctx layout [B, L, D]: ctx[b, i, h*64 + t]
        ctx[(size_t)(b * L_SEQ + i) * D_MODEL + h * DK + t] = r;
    }
}

extern "C" void kernel_launch(void* const* d_in, const int* in_sizes, int n_in,
                              void* d_out, int out_size, void* d_ws, size_t ws_size,
                              hipStream_t stream) {
    const float* query = (const float*)d_in[0];
    const float* key   = (const float*)d_in[1];
    const float* value = (const float*)d_in[2];
    const int*   mask  = (const int*)d_in[3];
    const float* relq  = (const float*)d_in[4];
    const float* relv  = (const float*)d_in[5];
    const float* Wq = (const float*)d_in[6];
    const float* bq = (const float*)d_in[7];
    const float* Wk = (const float*)d_in[8];
    const float* bk = (const float*)d_in[9];
    const float* Wv = (const float*)d_in[10];
    const float* bv = (const float*)d_in[11];
    const float* Wo = (const float*)d_in[12];
    const float* bo = (const float*)d_in[13];
    float* out = (float*)d_out;

    // workspace layout (floats): q, k, v [16,256,64] each, ctx [2,256,512]
    float* ws = (float*)d_ws;
    const size_t QKV = (size_t)BH * L_SEQ * DK;   // 262144
    float* q_ws   = ws;
    float* k_ws   = ws + QKV;
    float* v_ws   = ws + 2 * QKV;
    float* ctx_ws = ws + 3 * QKV;

    dim3 gg(16, 16, 1);
    gemm_nt<<<gg, 256, 0, stream>>>(query, Wq, bq, q_ws, 1);
    gemm_nt<<<gg, 256, 0, stream>>>(key,   Wk, bk, k_ws, 1);
    gemm_nt<<<gg, 256, 0, stream>>>(value, Wv, bv, v_ws, 1);

    attn_rel<<<BH * L_SEQ, 256, 0, stream>>>(q_ws, k_ws, v_ws, mask, relq, relv, ctx_ws);

    gemm_nt<<<gg, 256, 0, stream>>>(ctx_ws, Wo, bo, out, 0);
}

// Round 2
// 597.241 us; speedup vs baseline: 1.1003x; 1.1003x over previous
//
#include <hip/hip_runtime.h>
#include <hip/hip_bf16.h>

// Problem constants: B=2, L=256, D=512, H=8, dk=64
#define L_SEQ 256
#define D_MODEL 512
#define N_HEADS 8
#define DK 64
#define N_BATCH 2
#define BH (N_BATCH * N_HEADS)   // 16

// ---------------------------------------------------------------------------
// NT GEMM for the 512x512x512 projections. out[r,c] = X[r,:].W[c,:] + bias[c]
// grid.z selects (X,W,bias,out) triple so all of Q/K/V run in ONE launch
// (768 blocks = 3 blocks/CU = 12 waves/CU instead of 1 wave/SIMD).
// 32x32 tile, 2x2 register tile per thread, float4 (b128) LDS reads.
// ---------------------------------------------------------------------------
__global__ __launch_bounds__(256) void proj_gemm(
    const float* __restrict__ X0, const float* __restrict__ X1, const float* __restrict__ X2,
    const float* __restrict__ W0, const float* __restrict__ W1, const float* __restrict__ W2,
    const float* __restrict__ B0, const float* __restrict__ B1, const float* __restrict__ B2,
    float* __restrict__ O0, float* __restrict__ O1, float* __restrict__ O2,
    int split_heads)
{
    const int z = blockIdx.z;
    const float* X    = (z == 0) ? X0 : (z == 1) ? X1 : X2;
    const float* W    = (z == 0) ? W0 : (z == 1) ? W1 : W2;
    const float* bias = (z == 0) ? B0 : (z == 1) ? B1 : B2;
    float* out        = (z == 0) ? O0 : (z == 1) ? O1 : O2;

    __shared__ float Xs[32][36];   // stride 36 floats = 144 B (16B-aligned rows)
    __shared__ float Ws[32][36];

    const int t = threadIdx.x;
    const int row0 = blockIdx.x * 32;
    const int col0 = blockIdx.y * 32;
    const int lr = t >> 3;          // 0..31 (staging row)
    const int lc = (t & 7) << 2;    // 0..28 (staging col, float4)
    const int r0 = (t >> 4) * 2;    // 0..30 even (output rows r0, r0+1)
    const int c0 = (t & 15) * 2;    // 0..30 even (output cols c0, c0+1)

    float a00 = 0.f, a01 = 0.f, a10 = 0.f, a11 = 0.f;

    for (int k0 = 0; k0 < 512; k0 += 32) {
        __syncthreads();
        *(float4*)&Xs[lr][lc] = *(const float4*)&X[(size_t)(row0 + lr) * 512 + k0 + lc];
        *(float4*)&Ws[lr][lc] = *(const float4*)&W[(size_t)(col0 + lr) * 512 + k0 + lc];
        __syncthreads();
#pragma unroll
        for (int kk = 0; kk < 32; kk += 4) {
            const float4 x0 = *(const float4*)&Xs[r0][kk];
            const float4 x1 = *(const float4*)&Xs[r0 + 1][kk];
            const float4 w0 = *(const float4*)&Ws[c0][kk];
            const float4 w1 = *(const float4*)&Ws[c0 + 1][kk];
            a00 = fmaf(x0.x, w0.x, fmaf(x0.y, w0.y, fmaf(x0.z, w0.z, fmaf(x0.w, w0.w, a00))));
            a01 = fmaf(x0.x, w1.x, fmaf(x0.y, w1.y, fmaf(x0.z, w1.z, fmaf(x0.w, w1.w, a01))));
            a10 = fmaf(x1.x, w0.x, fmaf(x1.y, w0.y, fmaf(x1.z, w0.z, fmaf(x1.w, w0.w, a10))));
            a11 = fmaf(x1.x, w1.x, fmaf(x1.y, w1.y, fmaf(x1.z, w1.z, fmaf(x1.w, w1.w, a11))));
        }
    }

    const float accs[2][2] = {{a00, a01}, {a10, a11}};
#pragma unroll
    for (int dr = 0; dr < 2; ++dr) {
#pragma unroll
        for (int dc = 0; dc < 2; ++dc) {
            const int row = row0 + r0 + dr;
            const int c   = col0 + c0 + dc;
            const float val = accs[dr][dc] + bias[c];
            if (split_heads) {
                const int b = row >> 8, l = row & 255;
                const int h = c >> 6,  d = c & 63;
                out[(size_t)((b * N_HEADS + h) * L_SEQ + l) * DK + d] = val;
            } else {
                out[(size_t)row * 512 + c] = val;
            }
        }
    }
}

// ---------------------------------------------------------------------------
// Batched S0 = scale * q @ k^T.  q,k: [16,256,64].  S0: [16,256,256].
// grid (8,8,16) = 1024 blocks; 32x32 output tile, K=64 single pass.
// ---------------------------------------------------------------------------
__global__ __launch_bounds__(256) void qk_gemm(
    const float* __restrict__ q, const float* __restrict__ k,
    float* __restrict__ s0)
{
    __shared__ float Qs[32][68];
    __shared__ float Ks[32][68];

    const int bh = blockIdx.z;
    const int i0 = blockIdx.x * 32;
    const int j0 = blockIdx.y * 32;
    const int t = threadIdx.x;

    const int lr = t >> 3;           // 0..31
    const int lc0 = (t & 7) * 8;     // 0..56 (two float4s)
    {
        const float* qrow = q + ((size_t)(bh * L_SEQ + i0 + lr)) * DK;
        const float* krow = k + ((size_t)(bh * L_SEQ + j0 + lr)) * DK;
        *(float4*)&Qs[lr][lc0]     = *(const float4*)&qrow[lc0];
        *(float4*)&Qs[lr][lc0 + 4] = *(const float4*)&qrow[lc0 + 4];
        *(float4*)&Ks[lr][lc0]     = *(const float4*)&krow[lc0];
        *(float4*)&Ks[lr][lc0 + 4] = *(const float4*)&krow[lc0 + 4];
    }
    __syncthreads();

    const int r0 = (t >> 4) * 2;
    const int c0 = (t & 15) * 2;
    float a00 = 0.f, a01 = 0.f, a10 = 0.f, a11 = 0.f;
#pragma unroll
    for (int kk = 0; kk < 64; kk += 4) {
        const float4 x0 = *(const float4*)&Qs[r0][kk];
        const float4 x1 = *(const float4*)&Qs[r0 + 1][kk];
        const float4 w0 = *(const float4*)&Ks[c0][kk];
        const float4 w1 = *(const float4*)&Ks[c0 + 1][kk];
        a00 = fmaf(x0.x, w0.x, fmaf(x0.y, w0.y, fmaf(x0.z, w0.z, fmaf(x0.w, w0.w, a00))));
        a01 = fmaf(x0.x, w1.x, fmaf(x0.y, w1.y, fmaf(x0.z, w1.z, fmaf(x0.w, w1.w, a01))));
        a10 = fmaf(x1.x, w0.x, fmaf(x1.y, w0.y, fmaf(x1.z, w0.z, fmaf(x1.w, w0.w, a10))));
        a11 = fmaf(x1.x, w1.x, fmaf(x1.y, w1.y, fmaf(x1.z, w1.z, fmaf(x1.w, w1.w, a11))));
    }

    const float scale = 0.125f;
    const float accs[2][2] = {{a00, a01}, {a10, a11}};
#pragma unroll
    for (int dr = 0; dr < 2; ++dr)
#pragma unroll
        for (int dc = 0; dc < 2; ++dc)
            s0[((size_t)bh * L_SEQ + i0 + r0 + dr) * L_SEQ + j0 + c0 + dc] =
                accs[dr][dc] * scale;
}

// ---------------------------------------------------------------------------
// Streaming attention kernel. One block per (bh, i). Only relq/relv streams
// plus tiny S0/mask/p/ctxrel traffic — VMEM bytes/block halved vs R0.
// ---------------------------------------------------------------------------
__global__ __launch_bounds__(256) void attn_rel(
    const float* __restrict__ q, const int* __restrict__ mask,
    const float* __restrict__ relq, const float* __restrict__ relv,
    const float* __restrict__ s0, float* __restrict__ p_out,
    float* __restrict__ ctxrel)
{
    const int bh = blockIdx.x >> 8;    // 0..15
    const int i  = blockIdx.x & 255;
    const int b  = bh >> 3;
    const int h  = bh & 7;

    const int t    = threadIdx.x;
    const int lane = t & 63;
    const int wave = t >> 6;

    __shared__ float q_s[64];
    __shared__ float sc[256];
    __shared__ float red[8];
    __shared__ float ctxp[4][64];

    if (t < 64) q_s[t] = q[(size_t)(bh * L_SEQ + i) * DK + t];
    sc[t] = s0[((size_t)bh * L_SEQ + i) * L_SEQ + t];   // base scores
    __syncthreads();

    const int jgrp = t >> 4;          // 0..15
    const int d0   = (t & 15) << 2;   // 0..60

    const float q0 = q_s[d0], q1 = q_s[d0 + 1], q2 = q_s[d0 + 2], q3 = q_s[d0 + 3];

    const float* relq_row = relq + ((size_t)bh * L_SEQ + i) * L_SEQ * DK;
    const int* mask_row = mask + (size_t)(b * L_SEQ + i) * L_SEQ;

    // ---- scores: s_j = S0_j + sum_d q_d * relq_jd  (then mask) ----
#pragma unroll 4
    for (int p = 0; p < 16; ++p) {
        const int j = p * 16 + jgrp;
        float4 rq = *(const float4*)&relq_row[(size_t)j * DK + d0];
        float s = fmaf(q0, rq.x, fmaf(q1, rq.y, fmaf(q2, rq.z, q3 * rq.w)));
        s += __shfl_xor(s, 1);
        s += __shfl_xor(s, 2);
        s += __shfl_xor(s, 4);
        s += __shfl_xor(s, 8);
        if ((t & 15) == 0) {
            const int m = mask_row[j];
            sc[j] = (m == 0) ? -1e9f : (sc[j] + s);
        }
    }
    __syncthreads();

    // ---- softmax over 256 scores ----
    const float s_own = sc[t];
    float mval = s_own;
#pragma unroll
    for (int o = 32; o >= 1; o >>= 1) mval = fmaxf(mval, __shfl_xor(mval, o));
    if (lane == 0) red[wave] = mval;
    __syncthreads();
    mval = fmaxf(fmaxf(red[0], red[1]), fmaxf(red[2], red[3]));

    const float e = __expf(s_own - mval);
    float ssum = e;
#pragma unroll
    for (int o = 32; o >= 1; o >>= 1) ssum += __shfl_xor(ssum, o);
    if (lane == 0) red[4 + wave] = ssum;
    __syncthreads();
    ssum = red[4] + red[5] + red[6] + red[7];

    const float pfin = e / ssum;
    sc[t] = pfin;
    p_out[((size_t)bh * L_SEQ + i) * L_SEQ + t] = pfin;  // for pv_gemm
    __syncthreads();

    // ---- rel context: ctx_d = sum_j p_j * relv_jd ----
    const float* relv_row = relv + ((size_t)bh * L_SEQ + i) * L_SEQ * DK;

    float a0 = 0.f, a1 = 0.f, a2 = 0.f, a3 = 0.f;
#pragma unroll 4
    for (int p = 0; p < 16; ++p) {
        const int j = p * 16 + jgrp;
        float4 rv = *(const float4*)&relv_row[(size_t)j * DK + d0];
        const float pw = sc[j];
        a0 = fmaf(pw, rv.x, a0);
        a1 = fmaf(pw, rv.y, a1);
        a2 = fmaf(pw, rv.z, a2);
        a3 = fmaf(pw, rv.w, a3);
    }
    a0 += __shfl_xor(a0, 16); a0 += __shfl_xor(a0, 32);
    a1 += __shfl_xor(a1, 16); a1 += __shfl_xor(a1, 32);
    a2 += __shfl_xor(a2, 16); a2 += __shfl_xor(a2, 32);
    a3 += __shfl_xor(a3, 16); a3 += __shfl_xor(a3, 32);
    if (lane < 16) {
        ctxp[wave][lane * 4 + 0] = a0;
        ctxp[wave][lane * 4 + 1] = a1;
        ctxp[wave][lane * 4 + 2] = a2;
        ctxp[wave][lane * 4 + 3] = a3;
    }
    __syncthreads();

    if (t < 64) {
        const float r = ctxp[0][t] + ctxp[1][t] + ctxp[2][t] + ctxp[3][t];
        // [B, L, D] layout: ctxrel[b, i, h*64 + t]
        ctxrel[(size_t)(b * L_SEQ + i) * D_MODEL + h * DK + t] = r;
    }
}

// ---------------------------------------------------------------------------
// Batched ctx = P @ V + ctxrel, written in [B, L, D] layout.
// grid (8 row-tiles, 16 bh). P tile 32x256 in LDS; V staged 64 rows at a time.
// ---------------------------------------------------------------------------
__global__ __launch_bounds__(256) void pv_gemm(
    const float* __restrict__ P, const float* __restrict__ V,
    const float* __restrict__ ctxrel, float* __restrict__ ctx)
{
    __shared__ float Ps[32][260];
    __shared__ float Vs[64][68];

    const int bh = blockIdx.y;
    const int i0 = blockIdx.x * 32;
    const int b = bh >> 3, h = bh & 7;
    const int t = threadIdx.x;

    {   // load P tile: 32 rows x 256 cols
        const int lr  = t >> 3;         // 0..31
        const int lc0 = (t & 7) * 4;    // 0..28
        const float* prow = P + ((size_t)(bh * L_SEQ + i0 + lr)) * L_SEQ;
#pragma unroll
        for (int qq = 0; qq < 8; ++qq)
            *(float4*)&Ps[lr][lc0 + 32 * qq] = *(const float4*)&prow[lc0 + 32 * qq];
    }

    const int r0 = (t >> 4) * 2;     // rows r0, r0+1
    const int c0 = (t & 15) * 4;     // cols c0..c0+3

    float4 acc0 = {0.f, 0.f, 0.f, 0.f};
    float4 acc1 = {0.f, 0.f, 0.f, 0.f};

    for (int j0 = 0; j0 < 256; j0 += 64) {
        __syncthreads();
        {   // stage V rows j0..j0+63
            const int lr  = t >> 2;        // 0..63
            const int lc0 = (t & 3) * 4;   // 0,4,8,12
            const float* vrow = V + ((size_t)(bh * L_SEQ + j0 + lr)) * DK;
#pragma unroll
            for (int qq = 0; qq < 4; ++qq)
                *(float4*)&Vs[lr][lc0 + 16 * qq] = *(const float4*)&vrow[lc0 + 16 * qq];
        }
        __syncthreads();
#pragma unroll 8
        for (int jj = 0; jj < 64; ++jj) {
            const float4 vv = *(const float4*)&Vs[jj][c0];
            const float p0 = Ps[r0][j0 + jj];
            const float p1 = Ps[r0 + 1][j0 + jj];
            acc0.x = fmaf(p0, vv.x, acc0.x);
            acc0.y = fmaf(p0, vv.y, acc0.y);
            acc0.z = fmaf(p0, vv.z, acc0.z);
            acc0.w = fmaf(p0, vv.w, acc0.w);
            acc1.x = fmaf(p1, vv.x, acc1.x);
            acc1.y = fmaf(p1, vv.y, acc1.y);
            acc1.z = fmaf(p1, vv.z, acc1.z);
            acc1.w = fmaf(p1, vv.w, acc1.w);
        }
    }

#pragma unroll
    for (int dr = 0; dr < 2; ++dr) {
        const size_t base = ((size_t)(b * L_SEQ + i0 + r0 + dr)) * D_MODEL + h * DK + c0;
        const float4 rel = *(const float4*)&ctxrel[base];
        const float4 a = dr ? acc1 : acc0;
        float4 o;
        o.x = a.x + rel.x; o.y = a.y + rel.y; o.z = a.z + rel.z; o.w = a.w + rel.w;
        *(float4*)&ctx[base] = o;
    }
}

extern "C" void kernel_launch(void* const* d_in, const int* in_sizes, int n_in,
                              void* d_out, int out_size, void* d_ws, size_t ws_size,
                              hipStream_t stream) {
    const float* query = (const float*)d_in[0];
    const float* key   = (const float*)d_in[1];
    const float* value = (const float*)d_in[2];
    const int*   mask  = (const int*)d_in[3];
    const float* relq  = (const float*)d_in[4];
    const float* relv  = (const float*)d_in[5];
    const float* Wq = (const float*)d_in[6];
    const float* bq = (const float*)d_in[7];
    const float* Wk = (const float*)d_in[8];
    const float* bk = (const float*)d_in[9];
    const float* Wv = (const float*)d_in[10];
    const float* bv = (const float*)d_in[11];
    const float* Wo = (const float*)d_in[12];
    const float* bo = (const float*)d_in[13];
    float* out = (float*)d_out;

    // workspace layout (floats)
    float* ws = (float*)d_ws;
    const size_t QKV = (size_t)BH * L_SEQ * DK;       // 262144
    const size_t SSZ = (size_t)BH * L_SEQ * L_SEQ;    // 1048576
    float* q_ws      = ws;
    float* k_ws      = ws + QKV;
    float* v_ws      = ws + 2 * QKV;
    float* s0_ws     = ws + 3 * QKV;
    float* p_ws      = s0_ws + SSZ;
    float* ctxrel_ws = p_ws + SSZ;
    float* ctx_ws    = ctxrel_ws + QKV;               // total ~13.6 MB

    proj_gemm<<<dim3(16, 16, 3), 256, 0, stream>>>(
        query, key, value, Wq, Wk, Wv, bq, bk, bv, q_ws, k_ws, v_ws, 1);

    qk_gemm<<<dim3(8, 8, BH), 256, 0, stream>>>(q_ws, k_ws, s0_ws);

    attn_rel<<<BH * L_SEQ, 256, 0, stream>>>(q_ws, mask, relq, relv,
                                             s0_ws, p_ws, ctxrel_ws);

    pv_gemm<<<dim3(8, BH), 256, 0, stream>>>(p_ws, v_ws, ctxrel_ws, ctx_ws);

    proj_gemm<<<dim3(16, 16, 1), 256, 0, stream>>>(
        ctx_ws, ctx_ws, ctx_ws, Wo, Wo, Wo, bo, bo, bo, out, out, out, 0);
}

// Round 3
// 592.087 us; speedup vs baseline: 1.1099x; 1.0087x over previous
//
#include <hip/hip_runtime.h>
#include <hip/hip_bf16.h>

// Problem constants: B=2, L=256, D=512, H=8, dk=64
#define L_SEQ 256
#define D_MODEL 512
#define N_HEADS 8
#define DK 64
#define N_BATCH 2
#define BH (N_BATCH * N_HEADS)   // 16

// ---------------------------------------------------------------------------
// NT GEMM for the 512x512x512 projections. out[r,c] = X[r,:].W[c,:] + bias[c]
// grid.z selects (X,W,bias,out) triple so all of Q/K/V run in ONE launch.
// 32x32 tile, 2x2 register tile per thread, float4 (b128) LDS reads.
// ---------------------------------------------------------------------------
__global__ __launch_bounds__(256) void proj_gemm(
    const float* __restrict__ X0, const float* __restrict__ X1, const float* __restrict__ X2,
    const float* __restrict__ W0, const float* __restrict__ W1, const float* __restrict__ W2,
    const float* __restrict__ B0, const float* __restrict__ B1, const float* __restrict__ B2,
    float* __restrict__ O0, float* __restrict__ O1, float* __restrict__ O2,
    int split_heads)
{
    const int z = blockIdx.z;
    const float* X    = (z == 0) ? X0 : (z == 1) ? X1 : X2;
    const float* W    = (z == 0) ? W0 : (z == 1) ? W1 : W2;
    const float* bias = (z == 0) ? B0 : (z == 1) ? B1 : B2;
    float* out        = (z == 0) ? O0 : (z == 1) ? O1 : O2;

    __shared__ float Xs[32][36];
    __shared__ float Ws[32][36];

    const int t = threadIdx.x;
    const int row0 = blockIdx.x * 32;
    const int col0 = blockIdx.y * 32;
    const int lr = t >> 3;          // 0..31 (staging row)
    const int lc = (t & 7) << 2;    // 0..28 (staging col, float4)
    const int r0 = (t >> 4) * 2;    // output rows r0, r0+1
    const int c0 = (t & 15) * 2;    // output cols c0, c0+1

    float a00 = 0.f, a01 = 0.f, a10 = 0.f, a11 = 0.f;

    for (int k0 = 0; k0 < 512; k0 += 32) {
        __syncthreads();
        *(float4*)&Xs[lr][lc] = *(const float4*)&X[(size_t)(row0 + lr) * 512 + k0 + lc];
        *(float4*)&Ws[lr][lc] = *(const float4*)&W[(size_t)(col0 + lr) * 512 + k0 + lc];
        __syncthreads();
#pragma unroll
        for (int kk = 0; kk < 32; kk += 4) {
            const float4 x0 = *(const float4*)&Xs[r0][kk];
            const float4 x1 = *(const float4*)&Xs[r0 + 1][kk];
            const float4 w0 = *(const float4*)&Ws[c0][kk];
            const float4 w1 = *(const float4*)&Ws[c0 + 1][kk];
            a00 = fmaf(x0.x, w0.x, fmaf(x0.y, w0.y, fmaf(x0.z, w0.z, fmaf(x0.w, w0.w, a00))));
            a01 = fmaf(x0.x, w1.x, fmaf(x0.y, w1.y, fmaf(x0.z, w1.z, fmaf(x0.w, w1.w, a01))));
            a10 = fmaf(x1.x, w0.x, fmaf(x1.y, w0.y, fmaf(x1.z, w0.z, fmaf(x1.w, w0.w, a10))));
            a11 = fmaf(x1.x, w1.x, fmaf(x1.y, w1.y, fmaf(x1.z, w1.z, fmaf(x1.w, w1.w, a11))));
        }
    }

    const float accs[2][2] = {{a00, a01}, {a10, a11}};
#pragma unroll
    for (int dr = 0; dr < 2; ++dr) {
#pragma unroll
        for (int dc = 0; dc < 2; ++dc) {
            const int row = row0 + r0 + dr;
            const int c   = col0 + c0 + dc;
            const float val = accs[dr][dc] + bias[c];
            if (split_heads) {
                const int b = row >> 8, l = row & 255;
                const int h = c >> 6,  d = c & 63;
                out[(size_t)((b * N_HEADS + h) * L_SEQ + l) * DK + d] = val;
            } else {
                out[(size_t)row * 512 + c] = val;
            }
        }
    }
}

// ---------------------------------------------------------------------------
// Batched S0 = scale * q @ k^T.  q,k: [16,256,64].  S0: [16,256,256].
// ---------------------------------------------------------------------------
__global__ __launch_bounds__(256) void qk_gemm(
    const float* __restrict__ q, const float* __restrict__ k,
    float* __restrict__ s0)
{
    __shared__ float Qs[32][68];
    __shared__ float Ks[32][68];

    const int bh = blockIdx.z;
    const int i0 = blockIdx.x * 32;
    const int j0 = blockIdx.y * 32;
    const int t = threadIdx.x;

    const int lr = t >> 3;           // 0..31
    const int lc0 = (t & 7) * 8;     // two float4s
    {
        const float* qrow = q + ((size_t)(bh * L_SEQ + i0 + lr)) * DK;
        const float* krow = k + ((size_t)(bh * L_SEQ + j0 + lr)) * DK;
        *(float4*)&Qs[lr][lc0]     = *(const float4*)&qrow[lc0];
        *(float4*)&Qs[lr][lc0 + 4] = *(const float4*)&qrow[lc0 + 4];
        *(float4*)&Ks[lr][lc0]     = *(const float4*)&krow[lc0];
        *(float4*)&Ks[lr][lc0 + 4] = *(const float4*)&krow[lc0 + 4];
    }
    __syncthreads();

    const int r0 = (t >> 4) * 2;
    const int c0 = (t & 15) * 2;
    float a00 = 0.f, a01 = 0.f, a10 = 0.f, a11 = 0.f;
#pragma unroll
    for (int kk = 0; kk < 64; kk += 4) {
        const float4 x0 = *(const float4*)&Qs[r0][kk];
        const float4 x1 = *(const float4*)&Qs[r0 + 1][kk];
        const float4 w0 = *(const float4*)&Ks[c0][kk];
        const float4 w1 = *(const float4*)&Ks[c0 + 1][kk];
        a00 = fmaf(x0.x, w0.x, fmaf(x0.y, w0.y, fmaf(x0.z, w0.z, fmaf(x0.w, w0.w, a00))));
        a01 = fmaf(x0.x, w1.x, fmaf(x0.y, w1.y, fmaf(x0.z, w1.z, fmaf(x0.w, w1.w, a01))));
        a10 = fmaf(x1.x, w0.x, fmaf(x1.y, w0.y, fmaf(x1.z, w0.z, fmaf(x1.w, w0.w, a10))));
        a11 = fmaf(x1.x, w1.x, fmaf(x1.y, w1.y, fmaf(x1.z, w1.z, fmaf(x1.w, w1.w, a11))));
    }

    const float scale = 0.125f;
    const float accs[2][2] = {{a00, a01}, {a10, a11}};
#pragma unroll
    for (int dr = 0; dr < 2; ++dr)
#pragma unroll
        for (int dc = 0; dc < 2; ++dc)
            s0[((size_t)bh * L_SEQ + i0 + r0 + dr) * L_SEQ + j0 + c0 + dc] =
                accs[dr][dc] * scale;
}

// ---------------------------------------------------------------------------
// Streaming attention kernel. One block per (bh, i). Streams relq/relv once;
// at the measured per-CU VMEM ceiling (~10.6 B/cyc/CU) — do not disturb.
// ---------------------------------------------------------------------------
__global__ __launch_bounds__(256) void attn_rel(
    const float* __restrict__ q, const int* __restrict__ mask,
    const float* __restrict__ relq, const float* __restrict__ relv,
    const float* __restrict__ s0, float* __restrict__ p_out,
    float* __restrict__ ctxrel)
{
    const int bh = blockIdx.x >> 8;    // 0..15
    const int i  = blockIdx.x & 255;
    const int b  = bh >> 3;
    const int h  = bh & 7;

    const int t    = threadIdx.x;
    const int lane = t & 63;
    const int wave = t >> 6;

    __shared__ float q_s[64];
    __shared__ float sc[256];
    __shared__ float red[8];
    __shared__ float ctxp[4][64];

    if (t < 64) q_s[t] = q[(size_t)(bh * L_SEQ + i) * DK + t];
    sc[t] = s0[((size_t)bh * L_SEQ + i) * L_SEQ + t];   // base scores
    __syncthreads();

    const int jgrp = t >> 4;          // 0..15
    const int d0   = (t & 15) << 2;   // 0..60

    const float q0 = q_s[d0], q1 = q_s[d0 + 1], q2 = q_s[d0 + 2], q3 = q_s[d0 + 3];

    const float* relq_row = relq + ((size_t)bh * L_SEQ + i) * L_SEQ * DK;
    const int* mask_row = mask + (size_t)(b * L_SEQ + i) * L_SEQ;

    // ---- scores: s_j = S0_j + sum_d q_d * relq_jd  (then mask) ----
#pragma unroll 4
    for (int p = 0; p < 16; ++p) {
        const int j = p * 16 + jgrp;
        float4 rq = *(const float4*)&relq_row[(size_t)j * DK + d0];
        float s = fmaf(q0, rq.x, fmaf(q1, rq.y, fmaf(q2, rq.z, q3 * rq.w)));
        s += __shfl_xor(s, 1);
        s += __shfl_xor(s, 2);
        s += __shfl_xor(s, 4);
        s += __shfl_xor(s, 8);
        if ((t & 15) == 0) {
            const int m = mask_row[j];
            sc[j] = (m == 0) ? -1e9f : (sc[j] + s);
        }
    }
    __syncthreads();

    // ---- softmax over 256 scores ----
    const float s_own = sc[t];
    float mval = s_own;
#pragma unroll
    for (int o = 32; o >= 1; o >>= 1) mval = fmaxf(mval, __shfl_xor(mval, o));
    if (lane == 0) red[wave] = mval;
    __syncthreads();
    mval = fmaxf(fmaxf(red[0], red[1]), fmaxf(red[2], red[3]));

    const float e = __expf(s_own - mval);
    float ssum = e;
#pragma unroll
    for (int o = 32; o >= 1; o >>= 1) ssum += __shfl_xor(ssum, o);
    if (lane == 0) red[4 + wave] = ssum;
    __syncthreads();
    ssum = red[4] + red[5] + red[6] + red[7];

    const float pfin = e / ssum;
    sc[t] = pfin;
    p_out[((size_t)bh * L_SEQ + i) * L_SEQ + t] = pfin;  // for pv_gemm
    __syncthreads();

    // ---- rel context: ctx_d = sum_j p_j * relv_jd ----
    const float* relv_row = relv + ((size_t)bh * L_SEQ + i) * L_SEQ * DK;

    float a0 = 0.f, a1 = 0.f, a2 = 0.f, a3 = 0.f;
#pragma unroll 4
    for (int p = 0; p < 16; ++p) {
        const int j = p * 16 + jgrp;
        float4 rv = *(const float4*)&relv_row[(size_t)j * DK + d0];
        const float pw = sc[j];
        a0 = fmaf(pw, rv.x, a0);
        a1 = fmaf(pw, rv.y, a1);
        a2 = fmaf(pw, rv.z, a2);
        a3 = fmaf(pw, rv.w, a3);
    }
    a0 += __shfl_xor(a0, 16); a0 += __shfl_xor(a0, 32);
    a1 += __shfl_xor(a1, 16); a1 += __shfl_xor(a1, 32);
    a2 += __shfl_xor(a2, 16); a2 += __shfl_xor(a2, 32);
    a3 += __shfl_xor(a3, 16); a3 += __shfl_xor(a3, 32);
    if (lane < 16) {
        ctxp[wave][lane * 4 + 0] = a0;
        ctxp[wave][lane * 4 + 1] = a1;
        ctxp[wave][lane * 4 + 2] = a2;
        ctxp[wave][lane * 4 + 3] = a3;
    }
    __syncthreads();

    if (t < 64) {
        const float r = ctxp[0][t] + ctxp[1][t] + ctxp[2][t] + ctxp[3][t];
        ctxrel[(size_t)(b * L_SEQ + i) * D_MODEL + h * DK + t] = r;
    }
}

// ---------------------------------------------------------------------------
// Batched ctx = P @ V + ctxrel, written in [B, L, D] layout.
// R3: 16-row tiles -> grid (16, 16) = 256 blocks (1/CU) instead of 128.
// ---------------------------------------------------------------------------
__global__ __launch_bounds__(256) void pv_gemm(
    const float* __restrict__ P, const float* __restrict__ V,
    const float* __restrict__ ctxrel, float* __restrict__ ctx)
{
    __shared__ float Ps[16][260];
    __shared__ float Vs[64][68];

    const int bh = blockIdx.y;
    const int i0 = blockIdx.x * 16;
    const int b = bh >> 3, h = bh & 7;
    const int t = threadIdx.x;

    {   // load P tile: 16 rows x 256 cols (each thread: 4 float4s)
        const int lr  = t >> 4;         // 0..15
        const int lc0 = (t & 15) * 4;   // 0..60
        const float* prow = P + ((size_t)(bh * L_SEQ + i0 + lr)) * L_SEQ;
#pragma unroll
        for (int qq = 0; qq < 4; ++qq)
            *(float4*)&Ps[lr][lc0 + 64 * qq] = *(const float4*)&prow[lc0 + 64 * qq];
    }

    const int r  = t >> 4;           // output row 0..15
    const int c0 = (t & 15) * 4;     // output cols c0..c0+3

    float4 acc = {0.f, 0.f, 0.f, 0.f};

    for (int j0 = 0; j0 < 256; j0 += 64) {
        __syncthreads();
        {   // stage V rows j0..j0+63
            const int lr  = t >> 2;        // 0..63
            const int lc0 = (t & 3) * 4;   // 0,4,8,12
            const float* vrow = V + ((size_t)(bh * L_SEQ + j0 + lr)) * DK;
#pragma unroll
            for (int qq = 0; qq < 4; ++qq)
                *(float4*)&Vs[lr][lc0 + 16 * qq] = *(const float4*)&vrow[lc0 + 16 * qq];
        }
        __syncthreads();
#pragma unroll 8
        for (int jj = 0; jj < 64; ++jj) {
            const float4 vv = *(const float4*)&Vs[jj][c0];
            const float p0 = Ps[r][j0 + jj];
            acc.x = fmaf(p0, vv.x, acc.x);
            acc.y = fmaf(p0, vv.y, acc.y);
            acc.z = fmaf(p0, vv.z, acc.z);
            acc.w = fmaf(p0, vv.w, acc.w);
        }
    }

    {
        const size_t base = ((size_t)(b * L_SEQ + i0 + r)) * D_MODEL + h * DK + c0;
        const float4 rel = *(const float4*)&ctxrel[base];
        float4 o;
        o.x = acc.x + rel.x; o.y = acc.y + rel.y;
        o.z = acc.z + rel.z; o.w = acc.w + rel.w;
        *(float4*)&ctx[base] = o;
    }
}

extern "C" void kernel_launch(void* const* d_in, const int* in_sizes, int n_in,
                              void* d_out, int out_size, void* d_ws, size_t ws_size,
                              hipStream_t stream) {
    const float* query = (const float*)d_in[0];
    const float* key   = (const float*)d_in[1];
    const float* value = (const float*)d_in[2];
    const int*   mask  = (const int*)d_in[3];
    const float* relq  = (const float*)d_in[4];
    const float* relv  = (const float*)d_in[5];
    const float* Wq = (const float*)d_in[6];
    const float* bq = (const float*)d_in[7];
    const float* Wk = (const float*)d_in[8];
    const float* bk = (const float*)d_in[9];
    const float* Wv = (const float*)d_in[10];
    const float* bv = (const float*)d_in[11];
    const float* Wo = (const float*)d_in[12];
    const float* bo = (const float*)d_in[13];
    float* out = (float*)d_out;

    // workspace layout (floats)
    float* ws = (float*)d_ws;
    const size_t QKV = (size_t)BH * L_SEQ * DK;       // 262144
    const size_t SSZ = (size_t)BH * L_SEQ * L_SEQ;    // 1048576
    float* q_ws      = ws;
    float* k_ws      = ws + QKV;
    float* v_ws      = ws + 2 * QKV;
    float* s0_ws     = ws + 3 * QKV;
    float* p_ws      = s0_ws + SSZ;
    float* ctxrel_ws = p_ws + SSZ;
    float* ctx_ws    = ctxrel_ws + QKV;               // total ~13.6 MB

    proj_gemm<<<dim3(16, 16, 3), 256, 0, stream>>>(
        query, key, value, Wq, Wk, Wv, bq, bk, bv, q_ws, k_ws, v_ws, 1);

    qk_gemm<<<dim3(8, 8, BH), 256, 0, stream>>>(q_ws, k_ws, s0_ws);

    attn_rel<<<BH * L_SEQ, 256, 0, stream>>>(q_ws, mask, relq, relv,
                                             s0_ws, p_ws, ctxrel_ws);

    pv_gemm<<<dim3(16, BH), 256, 0, stream>>>(p_ws, v_ws, ctxrel_ws, ctx_ws);

    proj_gemm<<<dim3(16, 16, 1), 256, 0, stream>>>(
        ctx_ws, ctx_ws, ctx_ws, Wo, Wo, Wo, bo, bo, bo, out, out, out, 0);
}